// Round 8
// baseline (258.397 us; speedup 1.0000x reference)
//
#include <hip/hip_runtime.h>

typedef __attribute__((ext_vector_type(8))) short short8;
typedef __attribute__((ext_vector_type(4))) float f32x4;

#define DEV __device__ __forceinline__

// ---------- helpers ----------
DEV unsigned short f2bf(float f) {
    unsigned int u = __float_as_uint(f);
    u += 0x7FFFu + ((u >> 16) & 1u);   // round-to-nearest-even
    return (unsigned short)(u >> 16);
}
DEV float bf2f(unsigned short h) { return __uint_as_float(((unsigned int)h) << 16); }

DEV void gload16(const void* g, void* l) {
    __builtin_amdgcn_global_load_lds(
        (const __attribute__((address_space(1))) void*)(unsigned long long)g,
        (__attribute__((address_space(3))) void*)(unsigned int)(unsigned long long)l,
        16, 0, 0);
}

DEV void cast8(const float* in, unsigned short* out, size_t idx8) {
    const f32x4* p = (const f32x4*)in + idx8 * 2;
    f32x4 a = p[0], b = p[1];
    short8 v;
    v[0] = (short)f2bf(a[0]); v[1] = (short)f2bf(a[1]); v[2] = (short)f2bf(a[2]); v[3] = (short)f2bf(a[3]);
    v[4] = (short)f2bf(b[0]); v[5] = (short)f2bf(b[1]); v[6] = (short)f2bf(b[2]); v[7] = (short)f2bf(b[3]);
    *(short8*)(out + idx8 * 8) = v;
}

// ---------- merged init: cast x (8192 blk) + cast 4 W (2048 blk) + rope tables (32 blk) ----------
__global__ void init_kernel(const float* __restrict__ x,
                            const float* __restrict__ w0, const float* __restrict__ w1,
                            const float* __restrict__ w2, const float* __restrict__ w3,
                            unsigned short* __restrict__ xb,
                            unsigned short* __restrict__ o0, unsigned short* __restrict__ o1,
                            unsigned short* __restrict__ o2, unsigned short* __restrict__ o3,
                            float* __restrict__ cosT, float* __restrict__ sinT) {
    int blk = blockIdx.x;
    int tid = threadIdx.x;
    if (blk < 8192) {
        cast8(x, xb, (size_t)blk * 256 + tid);
    } else if (blk < 8192 + 2048) {
        int gid = (blk - 8192) * 256 + tid;  // 4 * 131072
        int sel = gid >> 17, idx = gid & 131071;
        const float* in = (sel == 0) ? w0 : (sel == 1) ? w1 : (sel == 2) ? w2 : w3;
        unsigned short* out = (sel == 0) ? o0 : (sel == 1) ? o1 : (sel == 2) ? o2 : o3;
        cast8(in, out, (size_t)idx);
    } else {
        int gid = (blk - 8192 - 2048) * 256 + tid;
        if (gid < 256 * 32) {
            int s = gid >> 5, i = gid & 31;
            float inv = powf(10000.0f, -(float)i * (1.0f / 32.0f));
            float f = (float)s * inv;
            cosT[gid] = cosf(f);
            sinT[gid] = sinf(f);
        }
    }
}

// =====================================================================
// 256x256 tile, BK=64 (2 K-halves of 32), 8 waves (2x4), 512 threads.
// Main loop = R2 4-phase, counted vmcnt(8), setprio (best measured).
// MODE 0 epilogue: LDS repack -> coalesced 16B stores (R6, verified).
// MODE 1 epilogue: NEW f32 LDS repack in two 128-row halves ->
//                  512B-contiguous float4 stores.
// =====================================================================
#define NT0 16  // K=1024 / 64

#define Ald(B, K) (SLDS + ((B) * 2 + (K)) * 8192)
#define Bld(B, K) (SLDS + 32768 + ((B) * 2 + (K)) * 8192)

#define STAGE2(SW, SBUF, SKH, TS) do {                                         \
    int ts_ = (TS) < NT0 ? (TS) : (NT0 - 1);                                   \
    const unsigned short* sp_ = SW##base + (size_t)ts_ * 64 + (SKH) * 32;      \
    gload16(sp_ + rel0, SW##ld(SBUF, SKH) + (size_t)tid * 8);                  \
    gload16(sp_ + rel1, SW##ld(SBUF, SKH) + (size_t)(tid + 512) * 8);          \
} while (0)

#define MM(MH, MI, NI)                                                         \
    acc[(MH)*4+(MI)][(NI)] = __builtin_amdgcn_mfma_f32_16x16x32_bf16(          \
        av##MI, bva[(NI)], acc[(MH)*4+(MI)][(NI)], 0, 0, 0)

#define PH0(BUF, KH, MH, SW, SBUF, SKH, TS, DW) do {                           \
    short8 av0 = *(const short8*)&Ald(BUF, KH)[aoff[(MH)*4 + 0]];              \
    short8 av1 = *(const short8*)&Ald(BUF, KH)[aoff[(MH)*4 + 1]];              \
    short8 av2 = *(const short8*)&Ald(BUF, KH)[aoff[(MH)*4 + 2]];              \
    short8 av3 = *(const short8*)&Ald(BUF, KH)[aoff[(MH)*4 + 3]];              \
    if ((MH) == 0) {                                                           \
        bva[0] = *(const short8*)&Bld(BUF, KH)[boff[0]];                       \
        bva[1] = *(const short8*)&Bld(BUF, KH)[boff[1]];                       \
        bva[2] = *(const short8*)&Bld(BUF, KH)[boff[2]];                       \
        bva[3] = *(const short8*)&Bld(BUF, KH)[boff[3]];                       \
    }                                                                          \
    STAGE2(SW, SBUF, SKH, TS);                                                 \
    if (DW) asm volatile("s_waitcnt vmcnt(8)" ::: "memory");                   \
    asm volatile("" ::: "memory");                                             \
    __builtin_amdgcn_s_barrier();                                              \
    asm volatile("" ::: "memory");                                             \
    __builtin_amdgcn_s_setprio(1);                                             \
    MM(MH,0,0); MM(MH,1,0); MM(MH,2,0); MM(MH,3,0);                            \
    MM(MH,0,1); MM(MH,1,1); MM(MH,2,1); MM(MH,3,1);                            \
    MM(MH,0,2); MM(MH,1,2); MM(MH,2,2); MM(MH,3,2);                            \
    MM(MH,0,3); MM(MH,1,3); MM(MH,2,3); MM(MH,3,3);                            \
    __builtin_amdgcn_s_setprio(0);                                             \
    asm volatile("" ::: "memory");                                             \
    __builtin_amdgcn_s_barrier();                                              \
    asm volatile("" ::: "memory");                                             \
} while (0)

#define TILE0(BUF, T)                                                          \
    PH0(BUF, 0, 0, A, (BUF)^1, 1, (T)+1, 0);                                   \
    PH0(BUF, 0, 1, B, (BUF)^1, 1, (T)+1, 1);                                   \
    PH0(BUF, 1, 0, A, (BUF),   0, (T)+2, 0);                                   \
    PH0(BUF, 1, 1, B, (BUF),   0, (T)+2, 1);

template <int MODE>
__global__ __launch_bounds__(512, 2) void gemm256_kernel(
    const unsigned short* __restrict__ A,
    const unsigned short* __restrict__ W0,
    const unsigned short* __restrict__ W1,
    const unsigned short* __restrict__ W2,
    unsigned short* __restrict__ q,
    unsigned short* __restrict__ k,
    unsigned short* __restrict__ vt,
    float* __restrict__ outF,
    const float* __restrict__ cosT,
    const float* __restrict__ sinT)
{
    __shared__ __align__(16) unsigned short SLDS[65536];  // 128 KB

    const int tid = threadIdx.x;
    const int l = tid & 63;
    const int w = tid >> 6;
    const int wr = w >> 2, wc = w & 3;
    const int l15 = l & 15, lg = l >> 4;

    const int nwg = gridDim.x;
    const int bid = blockIdx.x;
    const int cpx = nwg >> 3;
    const int swz = (bid & 7) * cpx + (bid >> 3);
    const int NBX = (MODE == 0) ? 12 : 4;
    const int bx = swz % NBX, by = swz / NBX;
    const int m0 = by * 256, n0 = bx * 256;

    const unsigned short* Bp;
    int nb = n0, sel = 3;
    if (MODE == 0) {
        sel = n0 >> 10;
        Bp = (sel == 0) ? W0 : ((sel == 1) ? W1 : W2);
        nb = n0 & 1023;
    } else {
        Bp = W0;
    }

    const int f0 = tid, f1 = tid + 512;
    const int rel0 = (f0 >> 2) * 1024 + (((f0 & 3) ^ ((f0 >> 3) & 3)) * 8);
    const int rel1 = (f1 >> 2) * 1024 + (((f1 & 3) ^ ((f1 >> 3) & 3)) * 8);
    const unsigned short* Abase = A + (size_t)m0 * 1024;
    const unsigned short* Bbase = Bp + (size_t)nb * 1024;

    int aoff[8], boff[4];
#pragma unroll
    for (int mi = 0; mi < 8; ++mi) {
        int row = wr * 128 + mi * 16 + l15;
        aoff[mi] = row * 32 + ((lg ^ ((row >> 1) & 3)) * 8);
    }
#pragma unroll
    for (int ni = 0; ni < 4; ++ni) {
        int row = wc * 64 + ni * 16 + l15;
        boff[ni] = row * 32 + ((lg ^ ((row >> 1) & 3)) * 8);
    }

    f32x4 acc[8][4];
#pragma unroll
    for (int mi = 0; mi < 8; ++mi)
#pragma unroll
        for (int ni = 0; ni < 4; ++ni)
#pragma unroll
            for (int e = 0; e < 4; ++e) acc[mi][ni][e] = 0.f;

    short8 bva[4];

    STAGE2(A, 0, 0, 0); STAGE2(B, 0, 0, 0);
    STAGE2(A, 0, 1, 0); STAGE2(B, 0, 1, 0);
    STAGE2(A, 1, 0, 1); STAGE2(B, 1, 0, 1);
    asm volatile("s_waitcnt vmcnt(8)" ::: "memory");
    asm volatile("" ::: "memory");
    __builtin_amdgcn_s_barrier();
    asm volatile("" ::: "memory");

#pragma unroll 1
    for (int it = 0; it < NT0 / 2; ++it) {
        const int t0 = it * 2;
        TILE0(0, t0);
        TILE0(1, t0 + 1);
    }

    // ---------------- epilogue ----------------
    asm volatile("s_waitcnt vmcnt(0)" ::: "memory");
    __syncthreads();

    if (MODE == 1) {
        // f32 coalesced epilogue via LDS, two 128-row halves
        char* lds = (char*)SLDS;
        const int lane32 = tid & 31, r16 = tid >> 5;
#pragma unroll 1
        for (int h2 = 0; h2 < 2; ++h2) {
            if (wr == h2) {
#pragma unroll
                for (int mi = 0; mi < 8; ++mi) {
#pragma unroll
                    for (int i = 0; i < 4; ++i) {
                        int rl = mi * 16 + lg * 4 + i;  // 0..127
#pragma unroll
                        for (int ni = 0; ni < 4; ++ni) {
                            int col = wc * 64 + ni * 16 + l15;
                            int byte = rl * 1024 + ((col * 4) ^ ((rl & 7) << 4));
                            *(float*)(lds + byte) = acc[mi][ni][i];
                        }
                    }
                }
            }
            __syncthreads();
#pragma unroll
            for (int it2 = 0; it2 < 16; ++it2) {
                int rl = (it2 & 7) * 16 + r16;
                int hf = it2 >> 3;
                int byte = rl * 1024 + ((hf * 512 + lane32 * 16) ^ ((rl & 7) << 4));
                f32x4 v = *(const f32x4*)(lds + byte);
                int grow = m0 + h2 * 128 + rl;
                int col = n0 + hf * 128 + lane32 * 4;
                *(f32x4*)(outF + (size_t)grow * 1024 + col) = v;
            }
            __syncthreads();
        }
        return;
    }

    // MODE 0: coalesced epilogue via LDS repack (R6, verified)
    const int b = m0 >> 8;

    if (sel < 2) {
#pragma unroll
        for (int mi = 0; mi < 8; ++mi) {
#pragma unroll
            for (int i = 0; i < 4; ++i) {
                int srow = wr * 128 + mi * 16 + lg * 4 + i;
                int s = srow & 255;
#pragma unroll
                for (int ni = 0; ni < 2; ++ni) {
                    int d = ni * 16 + l15;
                    float c = cosT[s * 32 + d], sn = sinT[s * 32 + d];
                    float lo = acc[mi][ni][i], hi = acc[mi][ni + 2][i];
                    acc[mi][ni][i] = lo * c - hi * sn;
                    acc[mi][ni + 2][i] = hi * c + lo * sn;
                }
#pragma unroll
                for (int ni = 0; ni < 4; ++ni) {
                    int col = wc * 64 + ni * 16 + l15;
                    int byte = srow * 512 + ((col * 2) ^ ((srow & 7) << 4));
                    *(unsigned short*)((char*)SLDS + byte) = f2bf(acc[mi][ni][i]);
                }
            }
        }
    } else {
#pragma unroll
        for (int mi = 0; mi < 8; ++mi) {
#pragma unroll
            for (int i = 0; i < 4; ++i) {
                int srow = wr * 128 + mi * 16 + lg * 4 + i;
#pragma unroll
                for (int ni = 0; ni < 4; ++ni) {
                    int col = wc * 64 + ni * 16 + l15;
                    int byte = col * 512 + ((srow * 2) ^ ((col & 7) << 4));
                    *(unsigned short*)((char*)SLDS + byte) = f2bf(acc[mi][ni][i]);
                }
            }
        }
    }
    __syncthreads();

    {
        const int r = tid >> 5, ct = tid & 31;
        unsigned short* dst01 = (sel == 0) ? q : k;
#pragma unroll
        for (int rg = 0; rg < 16; ++rg) {
            int row = rg * 16 + r;
            int byte = row * 512 + ((ct * 16) ^ ((row & 7) << 4));
            short8 v = *(const short8*)((char*)SLDS + byte);
            if (sel < 2) {
                int col = ct * 8;
                int h = (nb + col) >> 6, d = col & 63;
                *(short8*)(dst01 + (((size_t)(b * 16 + h) * 256 + row) * 64 + d)) = v;
            } else {
                int gc = nb + row;
                int h = gc >> 6, d = gc & 63;
                *(short8*)(vt + (((size_t)(b * 16 + h) * 64 + d) * 256 + ct * 8)) = v;
            }
        }
    }
}

// ---------- fused attention per (b,h): 8 waves x 32 q-rows, online softmax ----------
__global__ __launch_bounds__(512) void attn_kernel(
    const unsigned short* __restrict__ qp,   // (B,H,S,64) bf16, RoPE'd
    const unsigned short* __restrict__ kp,   // (B,H,S,64) bf16, RoPE'd
    const unsigned short* __restrict__ vtp,  // (B,H,64,S) bf16
    const int* __restrict__ mask,            // (B,S)
    unsigned short* __restrict__ ao)         // (B,S,1024) bf16
{
    __shared__ __align__(16) unsigned short Ks[128 * 64];
    __shared__ __align__(16) unsigned short Vts[64 * 128];
    __shared__ __align__(16) unsigned short Ps[8][32 * 64];  // per-wave private

    const int bh = blockIdx.x;
    const int b = bh >> 4, h = bh & 15;
    const int tid = threadIdx.x;
    const int l = tid & 63, w = tid >> 6;
    const int l15 = l & 15, lg = l >> 4;

    const unsigned short* kbase = kp + (size_t)bh * (256 * 64);
    const unsigned short* vtbase = vtp + (size_t)bh * (64 * 256);
    const unsigned short* qbase = qp + (size_t)bh * (256 * 64) + (size_t)(w * 32) * 64;

    short8 aq[2][2];
#pragma unroll
    for (int m = 0; m < 2; ++m)
#pragma unroll
        for (int ks = 0; ks < 2; ++ks)
            aq[m][ks] = *(const short8*)(qbase + (m * 16 + l15) * 64 + ks * 32 + lg * 8);

    float m_run[2][4], l_run[2][4];
    f32x4 o[2][4];
#pragma unroll
    for (int m = 0; m < 2; ++m)
#pragma unroll
        for (int i = 0; i < 4; ++i) { m_run[m][i] = -3.0e38f; l_run[m][i] = 0.f; }
#pragma unroll
    for (int m = 0; m < 2; ++m)
#pragma unroll
        for (int n = 0; n < 4; ++n)
#pragma unroll
            for (int e = 0; e < 4; ++e) o[m][n][e] = 0.f;

    const int* mrow = mask + b * 256;

    for (int half = 0; half < 2; ++half) {
        __syncthreads();  // guards restage vs prior tile reads
        for (int c2 = tid; c2 < 1024; c2 += 512) {
            int off = c2 * 16;
            int row = off >> 7, cb = off & 127;
            short8 v = *(const short8*)((const char*)kbase + (size_t)half * 16384 + off);
            *(short8*)((char*)Ks + row * 128 + (cb ^ ((row & 7) << 4))) = v;
        }
        for (int c2 = tid; c2 < 1024; c2 += 512) {
            int off = c2 * 16;
            int row = off >> 8, cb = off & 255;
            short8 v = *(const short8*)((const char*)vtbase + (size_t)row * 512 + half * 256 + cb);
            *(short8*)((char*)Vts + row * 256 + (cb ^ ((row & 7) << 4))) = v;
        }
        __syncthreads();

        for (int t2 = 0; t2 < 2; ++t2) {
            const int keyl = t2 * 64;
            const int keyg = half * 128 + keyl;

            f32x4 sf[2][4];
#pragma unroll
            for (int m = 0; m < 2; ++m)
#pragma unroll
                for (int n = 0; n < 4; ++n)
#pragma unroll
                    for (int e = 0; e < 4; ++e) sf[m][n][e] = 0.f;
#pragma unroll
            for (int ks = 0; ks < 2; ++ks) {
                short8 bk[4];
#pragma unroll
                for (int n = 0; n < 4; ++n) {
                    int row = keyl + n * 16 + l15;
                    int cb = (ks * 64 + lg * 16) ^ ((row & 7) << 4);
                    bk[n] = *(const short8*)((char*)Ks + row * 128 + cb);
                }
#pragma unroll
                for (int m = 0; m < 2; ++m)
#pragma unroll
                    for (int n = 0; n < 4; ++n)
                        sf[m][n] = __builtin_amdgcn_mfma_f32_16x16x32_bf16(aq[m][ks], bk[n], sf[m][n], 0, 0, 0);
            }
            float madd[4];
#pragma unroll
            for (int n = 0; n < 4; ++n) madd[n] = mrow[keyg + n * 16 + l15] ? 0.f : -1e30f;
#pragma unroll
            for (int m = 0; m < 2; ++m)
#pragma unroll
                for (int n = 0; n < 4; ++n)
#pragma unroll
                    for (int i = 0; i < 4; ++i) sf[m][n][i] = sf[m][n][i] * 0.125f + madd[n];
            float al[2][4];
#pragma unroll
            for (int m = 0; m < 2; ++m)
#pragma unroll
                for (int i = 0; i < 4; ++i) {
                    float mx = fmaxf(fmaxf(sf[m][0][i], sf[m][1][i]), fmaxf(sf[m][2][i], sf[m][3][i]));
                    mx = fmaxf(mx, __shfl_xor(mx, 1));
                    mx = fmaxf(mx, __shfl_xor(mx, 2));
                    mx = fmaxf(mx, __shfl_xor(mx, 4));
                    mx = fmaxf(mx, __shfl_xor(mx, 8));
                    float mnew = fmaxf(m_run[m][i], mx);
                    al[m][i] = __expf(m_run[m][i] - mnew);
                    m_run[m][i] = mnew;
                }
            float rs[2][4];
#pragma unroll
            for (int m = 0; m < 2; ++m)
#pragma unroll
                for (int i = 0; i < 4; ++i) rs[m][i] = 0.f;
#pragma unroll
            for (int m = 0; m < 2; ++m)
#pragma unroll
                for (int n = 0; n < 4; ++n)
#pragma unroll
                    for (int i = 0; i < 4; ++i) {
                        float p = __expf(sf[m][n][i] - m_run[m][i]);
                        sf[m][n][i] = p;
                        rs[m][i] += p;
                    }
#pragma unroll
            for (int m = 0; m < 2; ++m)
#pragma unroll
                for (int i = 0; i < 4; ++i) {
                    float r2 = rs[m][i];
                    r2 += __shfl_xor(r2, 1);
                    r2 += __shfl_xor(r2, 2);
                    r2 += __shfl_xor(r2, 4);
                    r2 += __shfl_xor(r2, 8);
                    l_run[m][i] = l_run[m][i] * al[m][i] + r2;
                }
#pragma unroll
            for (int m = 0; m < 2; ++m)
#pragma unroll
                for (int n = 0; n < 4; ++n)
#pragma unroll
                    for (int i = 0; i < 4; ++i) o[m][n][i] *= al[m][i];

            // P round-trip through wave-private Ps[w]: no block barriers needed
#pragma unroll
            for (int m = 0; m < 2; ++m)
#pragma unroll
                for (int n = 0; n < 4; ++n)
#pragma unroll
                    for (int i = 0; i < 4; ++i) {
                        int row = m * 16 + lg * 4 + i;
                        int cb = ((n * 16 + l15) * 2) ^ ((row & 7) << 4);
                        *(unsigned short*)((char*)Ps[w] + row * 128 + cb) = f2bf(sf[m][n][i]);
                    }
#pragma unroll
            for (int ks = 0; ks < 2; ++ks) {
                short8 pa[2];
#pragma unroll
                for (int m = 0; m < 2; ++m) {
                    int row = m * 16 + l15;
                    int cb = (ks * 64 + lg * 16) ^ ((row & 7) << 4);
                    pa[m] = *(const short8*)((char*)Ps[w] + row * 128 + cb);
                }
                short8 vb[4];
#pragma unroll
                for (int n = 0; n < 4; ++n) {
                    int row = n * 16 + l15;
                    int cb = (keyl * 2 + ks * 64 + lg * 16) ^ ((row & 7) << 4);
                    vb[n] = *(const short8*)((char*)Vts + row * 256 + cb);
                }
#pragma unroll
                for (int m = 0; m < 2; ++m)
#pragma unroll
                    for (int n = 0; n < 4; ++n)
                        o[m][n] = __builtin_amdgcn_mfma_f32_16x16x32_bf16(pa[m], vb[n], o[m][n], 0, 0, 0);
            }
        }
    }

    unsigned short* aop = ao + ((size_t)(b * 256 + w * 32)) * 1024 + h * 64;
#pragma unroll
    for (int m = 0; m < 2; ++m)
#pragma unroll
        for (int n = 0; n < 4; ++n)
#pragma unroll
            for (int i = 0; i < 4; ++i) {
                int row = m * 16 + lg * 4 + i;
                int d = n * 16 + l15;
                aop[(size_t)row * 1024 + d] = f2bf(o[m][n][i] / l_run[m][i]);
            }
}

// ---------- launch ----------
extern "C" void kernel_launch(void* const* d_in, const int* in_sizes, int n_in,
                              void* d_out, int out_size, void* d_ws, size_t ws_size,
                              hipStream_t stream) {
    const float* x = (const float*)d_in[0];
    const int* mask = (const int*)d_in[1];
    const float* Wq = (const float*)d_in[2];
    const float* Wk = (const float*)d_in[3];
    const float* Wv = (const float*)d_in[4];
    const float* Wo = (const float*)d_in[5];
    float* out = (float*)d_out;

    char* ws = (char*)d_ws;
    size_t off = 0;
    auto alloc = [&](size_t bytes) -> char* {
        char* p = ws + off;
        off = (off + bytes + 255) & ~(size_t)255;
        return p;
    };
    unsigned short* xb = (unsigned short*)alloc((size_t)16384 * 1024 * 2);  // bf16 x; later aliased as attn_out
    unsigned short* wqb = (unsigned short*)alloc((size_t)1024 * 1024 * 2);
    unsigned short* wkb = (unsigned short*)alloc((size_t)1024 * 1024 * 2);
    unsigned short* wvb = (unsigned short*)alloc((size_t)1024 * 1024 * 2);
    unsigned short* wob = (unsigned short*)alloc((size_t)1024 * 1024 * 2);
    unsigned short* q = (unsigned short*)alloc((size_t)16384 * 1024 * 2);   // (B,H,S,64)
    unsigned short* k = (unsigned short*)alloc((size_t)16384 * 1024 * 2);   // (B,H,S,64)
    unsigned short* vt = (unsigned short*)alloc((size_t)16384 * 1024 * 2);  // (B,H,64,S)
    float* cosT = (float*)alloc(256 * 32 * 4);
    float* sinT = (float*)alloc(256 * 32 * 4);

    init_kernel<<<8192 + 2048 + 32, 256, 0, stream>>>(x, Wq, Wk, Wv, Wo,
                                                      xb, wqb, wkb, wvb, wob, cosT, sinT);

    gemm256_kernel<0><<<768, 512, 0, stream>>>(xb, wqb, wkb, wvb, q, k, vt, nullptr, cosT, sinT);
    attn_kernel<<<1024, 512, 0, stream>>>(q, k, vt, mask, xb /* attn_out, aliases xb */);
    gemm256_kernel<1><<<256, 512, 0, stream>>>(xb, wob, nullptr, nullptr, nullptr, nullptr, nullptr, out, cosT, sinT);

    (void)in_sizes; (void)n_in; (void)out_size; (void)ws_size;
}

// Round 9
// 243.216 us; speedup vs baseline: 1.0624x; 1.0624x over previous
//
#include <hip/hip_runtime.h>

typedef __attribute__((ext_vector_type(8))) short short8;
typedef __attribute__((ext_vector_type(4))) float f32x4;

#define DEV __device__ __forceinline__

// ---------- helpers ----------
DEV unsigned short f2bf(float f) {
    unsigned int u = __float_as_uint(f);
    u += 0x7FFFu + ((u >> 16) & 1u);   // round-to-nearest-even
    return (unsigned short)(u >> 16);
}
DEV float bf2f(unsigned short h) { return __uint_as_float(((unsigned int)h) << 16); }

DEV void gload16(const void* g, void* l) {
    __builtin_amdgcn_global_load_lds(
        (const __attribute__((address_space(1))) void*)(unsigned long long)g,
        (__attribute__((address_space(3))) void*)(unsigned int)(unsigned long long)l,
        16, 0, 0);
}

DEV void cast8(const float* in, unsigned short* out, size_t idx8) {
    const f32x4* p = (const f32x4*)in + idx8 * 2;
    f32x4 a = p[0], b = p[1];
    short8 v;
    v[0] = (short)f2bf(a[0]); v[1] = (short)f2bf(a[1]); v[2] = (short)f2bf(a[2]); v[3] = (short)f2bf(a[3]);
    v[4] = (short)f2bf(b[0]); v[5] = (short)f2bf(b[1]); v[6] = (short)f2bf(b[2]); v[7] = (short)f2bf(b[3]);
    *(short8*)(out + idx8 * 8) = v;
}

// ---------- merged init: cast x (8192 blk) + cast 4 W (2048 blk) + rope tables (32 blk) ----------
__global__ void init_kernel(const float* __restrict__ x,
                            const float* __restrict__ w0, const float* __restrict__ w1,
                            const float* __restrict__ w2, const float* __restrict__ w3,
                            unsigned short* __restrict__ xb,
                            unsigned short* __restrict__ o0, unsigned short* __restrict__ o1,
                            unsigned short* __restrict__ o2, unsigned short* __restrict__ o3,
                            float* __restrict__ cosT, float* __restrict__ sinT) {
    int blk = blockIdx.x;
    int tid = threadIdx.x;
    if (blk < 8192) {
        cast8(x, xb, (size_t)blk * 256 + tid);
    } else if (blk < 8192 + 2048) {
        int gid = (blk - 8192) * 256 + tid;  // 4 * 131072
        int sel = gid >> 17, idx = gid & 131071;
        const float* in = (sel == 0) ? w0 : (sel == 1) ? w1 : (sel == 2) ? w2 : w3;
        unsigned short* out = (sel == 0) ? o0 : (sel == 1) ? o1 : (sel == 2) ? o2 : o3;
        cast8(in, out, (size_t)idx);
    } else {
        int gid = (blk - 8192 - 2048) * 256 + tid;
        if (gid < 256 * 32) {
            int s = gid >> 5, i = gid & 31;
            float inv = powf(10000.0f, -(float)i * (1.0f / 32.0f));
            float f = (float)s * inv;
            cosT[gid] = cosf(f);
            sinT[gid] = sinf(f);
        }
    }
}

// =====================================================================
// 256x256 tile, BK=64 (2 K-halves of 32), 8 waves (2x4), 512 threads.
// Main loop = R2 4-phase, counted vmcnt(8), setprio (best measured).
// MODE 0 epilogue: drain -> LDS repack -> coalesced 16B stores (R6).
// MODE 1 epilogue: R6 direct f32 stores (64B segments), NO drain (reverted
//                  R8's repack: it added +9us via serialization).
// =====================================================================
#define NT0 16  // K=1024 / 64

#define Ald(B, K) (SLDS + ((B) * 2 + (K)) * 8192)
#define Bld(B, K) (SLDS + 32768 + ((B) * 2 + (K)) * 8192)

#define STAGE2(SW, SBUF, SKH, TS) do {                                         \
    int ts_ = (TS) < NT0 ? (TS) : (NT0 - 1);                                   \
    const unsigned short* sp_ = SW##base + (size_t)ts_ * 64 + (SKH) * 32;      \
    gload16(sp_ + rel0, SW##ld(SBUF, SKH) + (size_t)tid * 8);                  \
    gload16(sp_ + rel1, SW##ld(SBUF, SKH) + (size_t)(tid + 512) * 8);          \
} while (0)

#define MM(MH, MI, NI)                                                         \
    acc[(MH)*4+(MI)][(NI)] = __builtin_amdgcn_mfma_f32_16x16x32_bf16(          \
        av##MI, bva[(NI)], acc[(MH)*4+(MI)][(NI)], 0, 0, 0)

#define PH0(BUF, KH, MH, SW, SBUF, SKH, TS, DW) do {                           \
    short8 av0 = *(const short8*)&Ald(BUF, KH)[aoff[(MH)*4 + 0]];              \
    short8 av1 = *(const short8*)&Ald(BUF, KH)[aoff[(MH)*4 + 1]];              \
    short8 av2 = *(const short8*)&Ald(BUF, KH)[aoff[(MH)*4 + 2]];              \
    short8 av3 = *(const short8*)&Ald(BUF, KH)[aoff[(MH)*4 + 3]];              \
    if ((MH) == 0) {                                                           \
        bva[0] = *(const short8*)&Bld(BUF, KH)[boff[0]];                       \
        bva[1] = *(const short8*)&Bld(BUF, KH)[boff[1]];                       \
        bva[2] = *(const short8*)&Bld(BUF, KH)[boff[2]];                       \
        bva[3] = *(const short8*)&Bld(BUF, KH)[boff[3]];                       \
    }                                                                          \
    STAGE2(SW, SBUF, SKH, TS);                                                 \
    if (DW) asm volatile("s_waitcnt vmcnt(8)" ::: "memory");                   \
    asm volatile("" ::: "memory");                                             \
    __builtin_amdgcn_s_barrier();                                              \
    asm volatile("" ::: "memory");                                             \
    __builtin_amdgcn_s_setprio(1);                                             \
    MM(MH,0,0); MM(MH,1,0); MM(MH,2,0); MM(MH,3,0);                            \
    MM(MH,0,1); MM(MH,1,1); MM(MH,2,1); MM(MH,3,1);                            \
    MM(MH,0,2); MM(MH,1,2); MM(MH,2,2); MM(MH,3,2);                            \
    MM(MH,0,3); MM(MH,1,3); MM(MH,2,3); MM(MH,3,3);                            \
    __builtin_amdgcn_s_setprio(0);                                             \
    asm volatile("" ::: "memory");                                             \
    __builtin_amdgcn_s_barrier();                                              \
    asm volatile("" ::: "memory");                                             \
} while (0)

#define TILE0(BUF, T)                                                          \
    PH0(BUF, 0, 0, A, (BUF)^1, 1, (T)+1, 0);                                   \
    PH0(BUF, 0, 1, B, (BUF)^1, 1, (T)+1, 1);                                   \
    PH0(BUF, 1, 0, A, (BUF),   0, (T)+2, 0);                                   \
    PH0(BUF, 1, 1, B, (BUF),   0, (T)+2, 1);

template <int MODE>
__global__ __launch_bounds__(512, 2) void gemm256_kernel(
    const unsigned short* __restrict__ A,
    const unsigned short* __restrict__ W0,
    const unsigned short* __restrict__ W1,
    const unsigned short* __restrict__ W2,
    unsigned short* __restrict__ q,
    unsigned short* __restrict__ k,
    unsigned short* __restrict__ vt,
    float* __restrict__ outF,
    const float* __restrict__ cosT,
    const float* __restrict__ sinT)
{
    __shared__ __align__(16) unsigned short SLDS[65536];  // 128 KB

    const int tid = threadIdx.x;
    const int l = tid & 63;
    const int w = tid >> 6;
    const int wr = w >> 2, wc = w & 3;
    const int l15 = l & 15, lg = l >> 4;

    const int nwg = gridDim.x;
    const int bid = blockIdx.x;
    const int cpx = nwg >> 3;
    const int swz = (bid & 7) * cpx + (bid >> 3);
    const int NBX = (MODE == 0) ? 12 : 4;
    const int bx = swz % NBX, by = swz / NBX;
    const int m0 = by * 256, n0 = bx * 256;

    const unsigned short* Bp;
    int nb = n0, sel = 3;
    if (MODE == 0) {
        sel = n0 >> 10;
        Bp = (sel == 0) ? W0 : ((sel == 1) ? W1 : W2);
        nb = n0 & 1023;
    } else {
        Bp = W0;
    }

    const int f0 = tid, f1 = tid + 512;
    const int rel0 = (f0 >> 2) * 1024 + (((f0 & 3) ^ ((f0 >> 3) & 3)) * 8);
    const int rel1 = (f1 >> 2) * 1024 + (((f1 & 3) ^ ((f1 >> 3) & 3)) * 8);
    const unsigned short* Abase = A + (size_t)m0 * 1024;
    const unsigned short* Bbase = Bp + (size_t)nb * 1024;

    int aoff[8], boff[4];
#pragma unroll
    for (int mi = 0; mi < 8; ++mi) {
        int row = wr * 128 + mi * 16 + l15;
        aoff[mi] = row * 32 + ((lg ^ ((row >> 1) & 3)) * 8);
    }
#pragma unroll
    for (int ni = 0; ni < 4; ++ni) {
        int row = wc * 64 + ni * 16 + l15;
        boff[ni] = row * 32 + ((lg ^ ((row >> 1) & 3)) * 8);
    }

    f32x4 acc[8][4];
#pragma unroll
    for (int mi = 0; mi < 8; ++mi)
#pragma unroll
        for (int ni = 0; ni < 4; ++ni)
#pragma unroll
            for (int e = 0; e < 4; ++e) acc[mi][ni][e] = 0.f;

    short8 bva[4];

    STAGE2(A, 0, 0, 0); STAGE2(B, 0, 0, 0);
    STAGE2(A, 0, 1, 0); STAGE2(B, 0, 1, 0);
    STAGE2(A, 1, 0, 1); STAGE2(B, 1, 0, 1);
    asm volatile("s_waitcnt vmcnt(8)" ::: "memory");
    asm volatile("" ::: "memory");
    __builtin_amdgcn_s_barrier();
    asm volatile("" ::: "memory");

#pragma unroll 1
    for (int it = 0; it < NT0 / 2; ++it) {
        const int t0 = it * 2;
        TILE0(0, t0);
        TILE0(1, t0 + 1);
    }

    // ---------------- epilogue ----------------
    if (MODE == 1) {
        // R6 path: direct f32 row-major stores, no drain needed first
#pragma unroll
        for (int mi = 0; mi < 8; ++mi) {
#pragma unroll
            for (int i = 0; i < 4; ++i) {
                int grow = m0 + wr * 128 + mi * 16 + lg * 4 + i;
#pragma unroll
                for (int ni = 0; ni < 4; ++ni) {
                    int col = n0 + wc * 64 + ni * 16 + l15;
                    outF[(size_t)grow * 1024 + col] = acc[mi][ni][i];
                }
            }
        }
        return;
    }

    // MODE 0: coalesced epilogue via LDS repack (R6, verified).
    // Outstanding gload_lds still target SLDS -> drain before reuse.
    asm volatile("s_waitcnt vmcnt(0)" ::: "memory");
    __syncthreads();

    const int b = m0 >> 8;

    if (sel < 2) {
#pragma unroll
        for (int mi = 0; mi < 8; ++mi) {
#pragma unroll
            for (int i = 0; i < 4; ++i) {
                int srow = wr * 128 + mi * 16 + lg * 4 + i;
                int s = srow & 255;
#pragma unroll
                for (int ni = 0; ni < 2; ++ni) {
                    int d = ni * 16 + l15;
                    float c = cosT[s * 32 + d], sn = sinT[s * 32 + d];
                    float lo = acc[mi][ni][i], hi = acc[mi][ni + 2][i];
                    acc[mi][ni][i] = lo * c - hi * sn;
                    acc[mi][ni + 2][i] = hi * c + lo * sn;
                }
#pragma unroll
                for (int ni = 0; ni < 4; ++ni) {
                    int col = wc * 64 + ni * 16 + l15;
                    int byte = srow * 512 + ((col * 2) ^ ((srow & 7) << 4));
                    *(unsigned short*)((char*)SLDS + byte) = f2bf(acc[mi][ni][i]);
                }
            }
        }
    } else {
#pragma unroll
        for (int mi = 0; mi < 8; ++mi) {
#pragma unroll
            for (int i = 0; i < 4; ++i) {
                int srow = wr * 128 + mi * 16 + lg * 4 + i;
#pragma unroll
                for (int ni = 0; ni < 4; ++ni) {
                    int col = wc * 64 + ni * 16 + l15;
                    int byte = col * 512 + ((srow * 2) ^ ((col & 7) << 4));
                    *(unsigned short*)((char*)SLDS + byte) = f2bf(acc[mi][ni][i]);
                }
            }
        }
    }
    __syncthreads();

    {
        const int r = tid >> 5, ct = tid & 31;
        unsigned short* dst01 = (sel == 0) ? q : k;
#pragma unroll
        for (int rg = 0; rg < 16; ++rg) {
            int row = rg * 16 + r;
            int byte = row * 512 + ((ct * 16) ^ ((row & 7) << 4));
            short8 v = *(const short8*)((char*)SLDS + byte);
            if (sel < 2) {
                int col = ct * 8;
                int h = (nb + col) >> 6, d = col & 63;
                *(short8*)(dst01 + (((size_t)(b * 16 + h) * 256 + row) * 64 + d)) = v;
            } else {
                int gc = nb + row;
                int h = gc >> 6, d = gc & 63;
                *(short8*)(vt + (((size_t)(b * 16 + h) * 64 + d) * 256 + ct * 8)) = v;
            }
        }
    }
}

// ---------- fused attention per (b,h): 8 waves x 32 q-rows, online softmax ----------
__global__ __launch_bounds__(512) void attn_kernel(
    const unsigned short* __restrict__ qp,   // (B,H,S,64) bf16, RoPE'd
    const unsigned short* __restrict__ kp,   // (B,H,S,64) bf16, RoPE'd
    const unsigned short* __restrict__ vtp,  // (B,H,64,S) bf16
    const int* __restrict__ mask,            // (B,S)
    unsigned short* __restrict__ ao)         // (B,S,1024) bf16
{
    __shared__ __align__(16) unsigned short Ks[128 * 64];
    __shared__ __align__(16) unsigned short Vts[64 * 128];
    __shared__ __align__(16) unsigned short Ps[8][32 * 64];  // per-wave private

    const int bh = blockIdx.x;
    const int b = bh >> 4, h = bh & 15;
    const int tid = threadIdx.x;
    const int l = tid & 63, w = tid >> 6;
    const int l15 = l & 15, lg = l >> 4;

    const unsigned short* kbase = kp + (size_t)bh * (256 * 64);
    const unsigned short* vtbase = vtp + (size_t)bh * (64 * 256);
    const unsigned short* qbase = qp + (size_t)bh * (256 * 64) + (size_t)(w * 32) * 64;

    short8 aq[2][2];
#pragma unroll
    for (int m = 0; m < 2; ++m)
#pragma unroll
        for (int ks = 0; ks < 2; ++ks)
            aq[m][ks] = *(const short8*)(qbase + (m * 16 + l15) * 64 + ks * 32 + lg * 8);

    float m_run[2][4], l_run[2][4];
    f32x4 o[2][4];
#pragma unroll
    for (int m = 0; m < 2; ++m)
#pragma unroll
        for (int i = 0; i < 4; ++i) { m_run[m][i] = -3.0e38f; l_run[m][i] = 0.f; }
#pragma unroll
    for (int m = 0; m < 2; ++m)
#pragma unroll
        for (int n = 0; n < 4; ++n)
#pragma unroll
            for (int e = 0; e < 4; ++e) o[m][n][e] = 0.f;

    const int* mrow = mask + b * 256;

    for (int half = 0; half < 2; ++half) {
        __syncthreads();  // guards restage vs prior tile reads
        for (int c2 = tid; c2 < 1024; c2 += 512) {
            int off = c2 * 16;
            int row = off >> 7, cb = off & 127;
            short8 v = *(const short8*)((const char*)kbase + (size_t)half * 16384 + off);
            *(short8*)((char*)Ks + row * 128 + (cb ^ ((row & 7) << 4))) = v;
        }
        for (int c2 = tid; c2 < 1024; c2 += 512) {
            int off = c2 * 16;
            int row = off >> 8, cb = off & 255;
            short8 v = *(const short8*)((const char*)vtbase + (size_t)row * 512 + half * 256 + cb);
            *(short8*)((char*)Vts + row * 256 + (cb ^ ((row & 7) << 4))) = v;
        }
        __syncthreads();

        for (int t2 = 0; t2 < 2; ++t2) {
            const int keyl = t2 * 64;
            const int keyg = half * 128 + keyl;

            f32x4 sf[2][4];
#pragma unroll
            for (int m = 0; m < 2; ++m)
#pragma unroll
                for (int n = 0; n < 4; ++n)
#pragma unroll
                    for (int e = 0; e < 4; ++e) sf[m][n][e] = 0.f;
#pragma unroll
            for (int ks = 0; ks < 2; ++ks) {
                short8 bk[4];
#pragma unroll
                for (int n = 0; n < 4; ++n) {
                    int row = keyl + n * 16 + l15;
                    int cb = (ks * 64 + lg * 16) ^ ((row & 7) << 4);
                    bk[n] = *(const short8*)((char*)Ks + row * 128 + cb);
                }
#pragma unroll
                for (int m = 0; m < 2; ++m)
#pragma unroll
                    for (int n = 0; n < 4; ++n)
                        sf[m][n] = __builtin_amdgcn_mfma_f32_16x16x32_bf16(aq[m][ks], bk[n], sf[m][n], 0, 0, 0);
            }
            float madd[4];
#pragma unroll
            for (int n = 0; n < 4; ++n) madd[n] = mrow[keyg + n * 16 + l15] ? 0.f : -1e30f;
#pragma unroll
            for (int m = 0; m < 2; ++m)
#pragma unroll
                for (int n = 0; n < 4; ++n)
#pragma unroll
                    for (int i = 0; i < 4; ++i) sf[m][n][i] = sf[m][n][i] * 0.125f + madd[n];
            float al[2][4];
#pragma unroll
            for (int m = 0; m < 2; ++m)
#pragma unroll
                for (int i = 0; i < 4; ++i) {
                    float mx = fmaxf(fmaxf(sf[m][0][i], sf[m][1][i]), fmaxf(sf[m][2][i], sf[m][3][i]));
                    mx = fmaxf(mx, __shfl_xor(mx, 1));
                    mx = fmaxf(mx, __shfl_xor(mx, 2));
                    mx = fmaxf(mx, __shfl_xor(mx, 4));
                    mx = fmaxf(mx, __shfl_xor(mx, 8));
                    float mnew = fmaxf(m_run[m][i], mx);
                    al[m][i] = __expf(m_run[m][i] - mnew);
                    m_run[m][i] = mnew;
                }
            float rs[2][4];
#pragma unroll
            for (int m = 0; m < 2; ++m)
#pragma unroll
                for (int i = 0; i < 4; ++i) rs[m][i] = 0.f;
#pragma unroll
            for (int m = 0; m < 2; ++m)
#pragma unroll
                for (int n = 0; n < 4; ++n)
#pragma unroll
                    for (int i = 0; i < 4; ++i) {
                        float p = __expf(sf[m][n][i] - m_run[m][i]);
                        sf[m][n][i] = p;
                        rs[m][i] += p;
                    }
#pragma unroll
            for (int m = 0; m < 2; ++m)
#pragma unroll
                for (int i = 0; i < 4; ++i) {
                    float r2 = rs[m][i];
                    r2 += __shfl_xor(r2, 1);
                    r2 += __shfl_xor(r2, 2);
                    r2 += __shfl_xor(r2, 4);
                    r2 += __shfl_xor(r2, 8);
                    l_run[m][i] = l_run[m][i] * al[m][i] + r2;
                }
#pragma unroll
            for (int m = 0; m < 2; ++m)
#pragma unroll
                for (int n = 0; n < 4; ++n)
#pragma unroll
                    for (int i = 0; i < 4; ++i) o[m][n][i] *= al[m][i];

            // P round-trip through wave-private Ps[w]: no block barriers needed
#pragma unroll
            for (int m = 0; m < 2; ++m)
#pragma unroll
                for (int n = 0; n < 4; ++n)
#pragma unroll
                    for (int i = 0; i < 4; ++i) {
                        int row = m * 16 + lg * 4 + i;
                        int cb = ((n * 16 + l15) * 2) ^ ((row & 7) << 4);
                        *(unsigned short*)((char*)Ps[w] + row * 128 + cb) = f2bf(sf[m][n][i]);
                    }
#pragma unroll
            for (int ks = 0; ks < 2; ++ks) {
                short8 pa[2];
#pragma unroll
                for (int m = 0; m < 2; ++m) {
                    int row = m * 16 + l15;
                    int cb = (ks * 64 + lg * 16) ^ ((row & 7) << 4);
                    pa[m] = *(const short8*)((char*)Ps[w] + row * 128 + cb);
                }
                short8 vb[4];
#pragma unroll
                for (int n = 0; n < 4; ++n) {
                    int row = n * 16 + l15;
                    int cb = (keyl * 2 + ks * 64 + lg * 16) ^ ((row & 7) << 4);
                    vb[n] = *(const short8*)((char*)Vts + row * 256 + cb);
                }
#pragma unroll
                for (int m = 0; m < 2; ++m)
#pragma unroll
                    for (int n = 0; n < 4; ++n)
                        o[m][n] = __builtin_amdgcn_mfma_f32_16x16x32_bf16(pa[m], vb[n], o[m][n], 0, 0, 0);
            }
        }
    }

    unsigned short* aop = ao + ((size_t)(b * 256 + w * 32)) * 1024 + h * 64;
#pragma unroll
    for (int m = 0; m < 2; ++m)
#pragma unroll
        for (int n = 0; n < 4; ++n)
#pragma unroll
            for (int i = 0; i < 4; ++i) {
                int row = m * 16 + lg * 4 + i;
                int d = n * 16 + l15;
                aop[(size_t)row * 1024 + d] = f2bf(o[m][n][i] / l_run[m][i]);
            }
}

// ---------- launch ----------
extern "C" void kernel_launch(void* const* d_in, const int* in_sizes, int n_in,
                              void* d_out, int out_size, void* d_ws, size_t ws_size,
                              hipStream_t stream) {
    const float* x = (const float*)d_in[0];
    const int* mask = (const int*)d_in[1];
    const float* Wq = (const float*)d_in[2];
    const float* Wk = (const float*)d_in[3];
    const float* Wv = (const float*)d_in[4];
    const float* Wo = (const float*)d_in[5];
    float* out = (float*)d_out;

    char* ws = (char*)d_ws;
    size_t off = 0;
    auto alloc = [&](size_t bytes) -> char* {
        char* p = ws + off;
        off = (off + bytes + 255) & ~(size_t)255;
        return p;
    };
    unsigned short* xb = (unsigned short*)alloc((size_t)16384 * 1024 * 2);  // bf16 x; later aliased as attn_out
    unsigned short* wqb = (unsigned short*)alloc((size_t)1024 * 1024 * 2);
    unsigned short* wkb = (unsigned short*)alloc((size_t)1024 * 1024 * 2);
    unsigned short* wvb = (unsigned short*)alloc((size_t)1024 * 1024 * 2);
    unsigned short* wob = (unsigned short*)alloc((size_t)1024 * 1024 * 2);
    unsigned short* q = (unsigned short*)alloc((size_t)16384 * 1024 * 2);   // (B,H,S,64)
    unsigned short* k = (unsigned short*)alloc((size_t)16384 * 1024 * 2);   // (B,H,S,64)
    unsigned short* vt = (unsigned short*)alloc((size_t)16384 * 1024 * 2);  // (B,H,64,S)
    float* cosT = (float*)alloc(256 * 32 * 4);
    float* sinT = (float*)alloc(256 * 32 * 4);

    init_kernel<<<8192 + 2048 + 32, 256, 0, stream>>>(x, Wq, Wk, Wv, Wo,
                                                      xb, wqb, wkb, wvb, wob, cosT, sinT);

    gemm256_kernel<0><<<768, 512, 0, stream>>>(xb, wqb, wkb, wvb, q, k, vt, nullptr, cosT, sinT);
    attn_kernel<<<1024, 512, 0, stream>>>(q, k, vt, mask, xb /* attn_out, aliases xb */);
    gemm256_kernel<1><<<256, 512, 0, stream>>>(xb, wob, nullptr, nullptr, nullptr, nullptr, nullptr, out, cosT, sinT);

    (void)in_sizes; (void)n_in; (void)out_size; (void)ws_size;
}

// Round 10
// 241.882 us; speedup vs baseline: 1.0683x; 1.0055x over previous
//
#include <hip/hip_runtime.h>

typedef __attribute__((ext_vector_type(8))) short short8;
typedef __attribute__((ext_vector_type(4))) float f32x4;

#define DEV __device__ __forceinline__

// ---------- helpers ----------
DEV unsigned short f2bf(float f) {
    unsigned int u = __float_as_uint(f);
    u += 0x7FFFu + ((u >> 16) & 1u);   // round-to-nearest-even
    return (unsigned short)(u >> 16);
}
DEV float bf2f(unsigned short h) { return __uint_as_float(((unsigned int)h) << 16); }

DEV void gload16(const void* g, void* l) {
    __builtin_amdgcn_global_load_lds(
        (const __attribute__((address_space(1))) void*)(unsigned long long)g,
        (__attribute__((address_space(3))) void*)(unsigned int)(unsigned long long)l,
        16, 0, 0);
}

DEV void cast8(const float* in, unsigned short* out, size_t idx8) {
    const f32x4* p = (const f32x4*)in + idx8 * 2;
    f32x4 a = p[0], b = p[1];
    short8 v;
    v[0] = (short)f2bf(a[0]); v[1] = (short)f2bf(a[1]); v[2] = (short)f2bf(a[2]); v[3] = (short)f2bf(a[3]);
    v[4] = (short)f2bf(b[0]); v[5] = (short)f2bf(b[1]); v[6] = (short)f2bf(b[2]); v[7] = (short)f2bf(b[3]);
    *(short8*)(out + idx8 * 8) = v;
}

// ---------- merged init: cast x (8192 blk) + cast 4 W (2048 blk) + rope tables (32 blk) ----------
__global__ void init_kernel(const float* __restrict__ x,
                            const float* __restrict__ w0, const float* __restrict__ w1,
                            const float* __restrict__ w2, const float* __restrict__ w3,
                            unsigned short* __restrict__ xb,
                            unsigned short* __restrict__ o0, unsigned short* __restrict__ o1,
                            unsigned short* __restrict__ o2, unsigned short* __restrict__ o3,
                            float* __restrict__ cosT, float* __restrict__ sinT) {
    int blk = blockIdx.x;
    int tid = threadIdx.x;
    if (blk < 8192) {
        cast8(x, xb, (size_t)blk * 256 + tid);
    } else if (blk < 8192 + 2048) {
        int gid = (blk - 8192) * 256 + tid;  // 4 * 131072
        int sel = gid >> 17, idx = gid & 131071;
        const float* in = (sel == 0) ? w0 : (sel == 1) ? w1 : (sel == 2) ? w2 : w3;
        unsigned short* out = (sel == 0) ? o0 : (sel == 1) ? o1 : (sel == 2) ? o2 : o3;
        cast8(in, out, (size_t)idx);
    } else {
        int gid = (blk - 8192 - 2048) * 256 + tid;
        if (gid < 256 * 32) {
            int s = gid >> 5, i = gid & 31;
            float inv = powf(10000.0f, -(float)i * (1.0f / 32.0f));
            float f = (float)s * inv;
            cosT[gid] = cosf(f);
            sinT[gid] = sinf(f);
        }
    }
}

// =====================================================================
// 256x256 tile, BK=64 (2 K-halves of 32), 8 waves (2x4), 512 threads.
// Main loop = R2 4-phase, counted vmcnt(8), setprio (best measured).
// MODE 0 epilogue: drain -> LDS repack -> coalesced 16B stores (R6).
// MODE 1 epilogue: direct f32 stores (R6; R8 repack regressed, reverted).
// =====================================================================
#define NT0 16  // K=1024 / 64

#define Ald(B, K) (SLDS + ((B) * 2 + (K)) * 8192)
#define Bld(B, K) (SLDS + 32768 + ((B) * 2 + (K)) * 8192)

#define STAGE2(SW, SBUF, SKH, TS) do {                                         \
    int ts_ = (TS) < NT0 ? (TS) : (NT0 - 1);                                   \
    const unsigned short* sp_ = SW##base + (size_t)ts_ * 64 + (SKH) * 32;      \
    gload16(sp_ + rel0, SW##ld(SBUF, SKH) + (size_t)tid * 8);                  \
    gload16(sp_ + rel1, SW##ld(SBUF, SKH) + (size_t)(tid + 512) * 8);          \
} while (0)

#define MM(MH, MI, NI)                                                         \
    acc[(MH)*4+(MI)][(NI)] = __builtin_amdgcn_mfma_f32_16x16x32_bf16(          \
        av##MI, bva[(NI)], acc[(MH)*4+(MI)][(NI)], 0, 0, 0)

#define PH0(BUF, KH, MH, SW, SBUF, SKH, TS, DW) do {                           \
    short8 av0 = *(const short8*)&Ald(BUF, KH)[aoff[(MH)*4 + 0]];              \
    short8 av1 = *(const short8*)&Ald(BUF, KH)[aoff[(MH)*4 + 1]];              \
    short8 av2 = *(const short8*)&Ald(BUF, KH)[aoff[(MH)*4 + 2]];              \
    short8 av3 = *(const short8*)&Ald(BUF, KH)[aoff[(MH)*4 + 3]];              \
    if ((MH) == 0) {                                                           \
        bva[0] = *(const short8*)&Bld(BUF, KH)[boff[0]];                       \
        bva[1] = *(const short8*)&Bld(BUF, KH)[boff[1]];                       \
        bva[2] = *(const short8*)&Bld(BUF, KH)[boff[2]];                       \
        bva[3] = *(const short8*)&Bld(BUF, KH)[boff[3]];                       \
    }                                                                          \
    STAGE2(SW, SBUF, SKH, TS);                                                 \
    if (DW) asm volatile("s_waitcnt vmcnt(8)" ::: "memory");                   \
    asm volatile("" ::: "memory");                                             \
    __builtin_amdgcn_s_barrier();                                              \
    asm volatile("" ::: "memory");                                             \
    __builtin_amdgcn_s_setprio(1);                                             \
    MM(MH,0,0); MM(MH,1,0); MM(MH,2,0); MM(MH,3,0);                            \
    MM(MH,0,1); MM(MH,1,1); MM(MH,2,1); MM(MH,3,1);                            \
    MM(MH,0,2); MM(MH,1,2); MM(MH,2,2); MM(MH,3,2);                            \
    MM(MH,0,3); MM(MH,1,3); MM(MH,2,3); MM(MH,3,3);                            \
    __builtin_amdgcn_s_setprio(0);                                             \
    asm volatile("" ::: "memory");                                             \
    __builtin_amdgcn_s_barrier();                                              \
    asm volatile("" ::: "memory");                                             \
} while (0)

#define TILE0(BUF, T)                                                          \
    PH0(BUF, 0, 0, A, (BUF)^1, 1, (T)+1, 0);                                   \
    PH0(BUF, 0, 1, B, (BUF)^1, 1, (T)+1, 1);                                   \
    PH0(BUF, 1, 0, A, (BUF),   0, (T)+2, 0);                                   \
    PH0(BUF, 1, 1, B, (BUF),   0, (T)+2, 1);

template <int MODE>
__global__ __launch_bounds__(512, 2) void gemm256_kernel(
    const unsigned short* __restrict__ A,
    const unsigned short* __restrict__ W0,
    const unsigned short* __restrict__ W1,
    const unsigned short* __restrict__ W2,
    unsigned short* __restrict__ q,
    unsigned short* __restrict__ k,
    unsigned short* __restrict__ vt,
    float* __restrict__ outF,
    const float* __restrict__ cosT,
    const float* __restrict__ sinT)
{
    __shared__ __align__(16) unsigned short SLDS[65536];  // 128 KB

    const int tid = threadIdx.x;
    const int l = tid & 63;
    const int w = tid >> 6;
    const int wr = w >> 2, wc = w & 3;
    const int l15 = l & 15, lg = l >> 4;

    const int nwg = gridDim.x;
    const int bid = blockIdx.x;
    const int cpx = nwg >> 3;
    const int swz = (bid & 7) * cpx + (bid >> 3);
    const int NBX = (MODE == 0) ? 12 : 4;
    const int bx = swz % NBX, by = swz / NBX;
    const int m0 = by * 256, n0 = bx * 256;

    const unsigned short* Bp;
    int nb = n0, sel = 3;
    if (MODE == 0) {
        sel = n0 >> 10;
        Bp = (sel == 0) ? W0 : ((sel == 1) ? W1 : W2);
        nb = n0 & 1023;
    } else {
        Bp = W0;
    }

    const int f0 = tid, f1 = tid + 512;
    const int rel0 = (f0 >> 2) * 1024 + (((f0 & 3) ^ ((f0 >> 3) & 3)) * 8);
    const int rel1 = (f1 >> 2) * 1024 + (((f1 & 3) ^ ((f1 >> 3) & 3)) * 8);
    const unsigned short* Abase = A + (size_t)m0 * 1024;
    const unsigned short* Bbase = Bp + (size_t)nb * 1024;

    int aoff[8], boff[4];
#pragma unroll
    for (int mi = 0; mi < 8; ++mi) {
        int row = wr * 128 + mi * 16 + l15;
        aoff[mi] = row * 32 + ((lg ^ ((row >> 1) & 3)) * 8);
    }
#pragma unroll
    for (int ni = 0; ni < 4; ++ni) {
        int row = wc * 64 + ni * 16 + l15;
        boff[ni] = row * 32 + ((lg ^ ((row >> 1) & 3)) * 8);
    }

    f32x4 acc[8][4];
#pragma unroll
    for (int mi = 0; mi < 8; ++mi)
#pragma unroll
        for (int ni = 0; ni < 4; ++ni)
#pragma unroll
            for (int e = 0; e < 4; ++e) acc[mi][ni][e] = 0.f;

    short8 bva[4];

    STAGE2(A, 0, 0, 0); STAGE2(B, 0, 0, 0);
    STAGE2(A, 0, 1, 0); STAGE2(B, 0, 1, 0);
    STAGE2(A, 1, 0, 1); STAGE2(B, 1, 0, 1);
    asm volatile("s_waitcnt vmcnt(8)" ::: "memory");
    asm volatile("" ::: "memory");
    __builtin_amdgcn_s_barrier();
    asm volatile("" ::: "memory");

#pragma unroll 1
    for (int it = 0; it < NT0 / 2; ++it) {
        const int t0 = it * 2;
        TILE0(0, t0);
        TILE0(1, t0 + 1);
    }

    // ---------------- epilogue ----------------
    if (MODE == 1) {
        // direct f32 row-major stores (64B segments), no drain first
#pragma unroll
        for (int mi = 0; mi < 8; ++mi) {
#pragma unroll
            for (int i = 0; i < 4; ++i) {
                int grow = m0 + wr * 128 + mi * 16 + lg * 4 + i;
#pragma unroll
                for (int ni = 0; ni < 4; ++ni) {
                    int col = n0 + wc * 64 + ni * 16 + l15;
                    outF[(size_t)grow * 1024 + col] = acc[mi][ni][i];
                }
            }
        }
        return;
    }

    // MODE 0: coalesced epilogue via LDS repack (R6, verified).
    asm volatile("s_waitcnt vmcnt(0)" ::: "memory");
    __syncthreads();

    const int b = m0 >> 8;

    if (sel < 2) {
#pragma unroll
        for (int mi = 0; mi < 8; ++mi) {
#pragma unroll
            for (int i = 0; i < 4; ++i) {
                int srow = wr * 128 + mi * 16 + lg * 4 + i;
                int s = srow & 255;
#pragma unroll
                for (int ni = 0; ni < 2; ++ni) {
                    int d = ni * 16 + l15;
                    float c = cosT[s * 32 + d], sn = sinT[s * 32 + d];
                    float lo = acc[mi][ni][i], hi = acc[mi][ni + 2][i];
                    acc[mi][ni][i] = lo * c - hi * sn;
                    acc[mi][ni + 2][i] = hi * c + lo * sn;
                }
#pragma unroll
                for (int ni = 0; ni < 4; ++ni) {
                    int col = wc * 64 + ni * 16 + l15;
                    int byte = srow * 512 + ((col * 2) ^ ((srow & 7) << 4));
                    *(unsigned short*)((char*)SLDS + byte) = f2bf(acc[mi][ni][i]);
                }
            }
        }
    } else {
#pragma unroll
        for (int mi = 0; mi < 8; ++mi) {
#pragma unroll
            for (int i = 0; i < 4; ++i) {
                int srow = wr * 128 + mi * 16 + lg * 4 + i;
#pragma unroll
                for (int ni = 0; ni < 4; ++ni) {
                    int col = wc * 64 + ni * 16 + l15;
                    int byte = col * 512 + ((srow * 2) ^ ((col & 7) << 4));
                    *(unsigned short*)((char*)SLDS + byte) = f2bf(acc[mi][ni][i]);
                }
            }
        }
    }
    __syncthreads();

    {
        const int r = tid >> 5, ct = tid & 31;
        unsigned short* dst01 = (sel == 0) ? q : k;
#pragma unroll
        for (int rg = 0; rg < 16; ++rg) {
            int row = rg * 16 + r;
            int byte = row * 512 + ((ct * 16) ^ ((row & 7) << 4));
            short8 v = *(const short8*)((char*)SLDS + byte);
            if (sel < 2) {
                int col = ct * 8;
                int h = (nb + col) >> 6, d = col & 63;
                *(short8*)(dst01 + (((size_t)(b * 16 + h) * 256 + row) * 64 + d)) = v;
            } else {
                int gc = nb + row;
                int h = gc >> 6, d = gc & 63;
                *(short8*)(vt + (((size_t)(b * 16 + h) * 64 + d) * 256 + ct * 8)) = v;
            }
        }
    }
}

// ---------- attn staging helpers (T14 split: load-to-reg / write-to-LDS) ----------
DEV void attn_load_half(const unsigned short* kbase, const unsigned short* vtbase,
                        int half, int tid, short8 kr[2], short8 vr[2]) {
#pragma unroll
    for (int i = 0; i < 2; ++i) {
        int off = (tid + i * 512) * 16;
        kr[i] = *(const short8*)((const char*)kbase + (size_t)half * 16384 + off);
        vr[i] = *(const short8*)((const char*)vtbase + (size_t)(off >> 8) * 512 + half * 256 + (off & 255));
    }
}
DEV void attn_store_half(char* Ks, char* Vts, int tid, const short8 kr[2], const short8 vr[2]) {
#pragma unroll
    for (int i = 0; i < 2; ++i) {
        int off = (tid + i * 512) * 16;
        int krow = off >> 7, kcb = off & 127;
        *(short8*)(Ks + krow * 128 + (kcb ^ ((krow & 7) << 4))) = kr[i];
        int vrow = off >> 8, vcb = off & 255;
        *(short8*)(Vts + vrow * 256 + (vcb ^ ((vrow & 7) << 4))) = vr[i];
    }
}

// ---------- fused attention per (b,h): 8 waves x 32 q-rows, online softmax ----------
__global__ __launch_bounds__(512) void attn_kernel(
    const unsigned short* __restrict__ qp,   // (B,H,S,64) bf16, RoPE'd
    const unsigned short* __restrict__ kp,   // (B,H,S,64) bf16, RoPE'd
    const unsigned short* __restrict__ vtp,  // (B,H,64,S) bf16
    const int* __restrict__ mask,            // (B,S)
    unsigned short* __restrict__ ao)         // (B,S,1024) bf16
{
    __shared__ __align__(16) unsigned short Ks[128 * 64];
    __shared__ __align__(16) unsigned short Vts[64 * 128];
    __shared__ __align__(16) unsigned short Ps[8][32 * 64];  // per-wave private

    const int bh = blockIdx.x;
    const int b = bh >> 4, h = bh & 15;
    const int tid = threadIdx.x;
    const int l = tid & 63, w = tid >> 6;
    const int l15 = l & 15, lg = l >> 4;

    const unsigned short* kbase = kp + (size_t)bh * (256 * 64);
    const unsigned short* vtbase = vtp + (size_t)bh * (64 * 256);
    const unsigned short* qbase = qp + (size_t)bh * (256 * 64) + (size_t)(w * 32) * 64;

    short8 aq[2][2];
#pragma unroll
    for (int m = 0; m < 2; ++m)
#pragma unroll
        for (int ks = 0; ks < 2; ++ks)
            aq[m][ks] = *(const short8*)(qbase + (m * 16 + l15) * 64 + ks * 32 + lg * 8);

    float m_run[2][4], l_run[2][4];
    f32x4 o[2][4];
#pragma unroll
    for (int m = 0; m < 2; ++m)
#pragma unroll
        for (int i = 0; i < 4; ++i) { m_run[m][i] = -3.0e38f; l_run[m][i] = 0.f; }
#pragma unroll
    for (int m = 0; m < 2; ++m)
#pragma unroll
        for (int n = 0; n < 4; ++n)
#pragma unroll
            for (int e = 0; e < 4; ++e) o[m][n][e] = 0.f;

    const int* mrow = mask + b * 256;

    // T14: stage half 0 now, prefetch half 1 to registers (HBM latency
    // overlaps half-0 compute); write half 1 after half-0's last LDS read.
    short8 krA[2], vrA[2], krB[2], vrB[2];
    attn_load_half(kbase, vtbase, 0, tid, krA, vrA);
    attn_store_half((char*)Ks, (char*)Vts, tid, krA, vrA);
    attn_load_half(kbase, vtbase, 1, tid, krB, vrB);

    for (int half = 0; half < 2; ++half) {
        if (half == 1) {
            __syncthreads();  // all waves done reading half-0 Ks/Vts
            attn_store_half((char*)Ks, (char*)Vts, tid, krB, vrB);
        }
        __syncthreads();      // staged data visible

        for (int t2 = 0; t2 < 2; ++t2) {
            const int keyl = t2 * 64;
            const int keyg = half * 128 + keyl;

            f32x4 sf[2][4];
#pragma unroll
            for (int m = 0; m < 2; ++m)
#pragma unroll
                for (int n = 0; n < 4; ++n)
#pragma unroll
                    for (int e = 0; e < 4; ++e) sf[m][n][e] = 0.f;
#pragma unroll
            for (int ks = 0; ks < 2; ++ks) {
                short8 bk[4];
#pragma unroll
                for (int n = 0; n < 4; ++n) {
                    int row = keyl + n * 16 + l15;
                    int cb = (ks * 64 + lg * 16) ^ ((row & 7) << 4);
                    bk[n] = *(const short8*)((char*)Ks + row * 128 + cb);
                }
#pragma unroll
                for (int m = 0; m < 2; ++m)
#pragma unroll
                    for (int n = 0; n < 4; ++n)
                        sf[m][n] = __builtin_amdgcn_mfma_f32_16x16x32_bf16(aq[m][ks], bk[n], sf[m][n], 0, 0, 0);
            }
            float madd[4];
#pragma unroll
            for (int n = 0; n < 4; ++n) madd[n] = mrow[keyg + n * 16 + l15] ? 0.f : -1e30f;
#pragma unroll
            for (int m = 0; m < 2; ++m)
#pragma unroll
                for (int n = 0; n < 4; ++n)
#pragma unroll
                    for (int i = 0; i < 4; ++i) sf[m][n][i] = sf[m][n][i] * 0.125f + madd[n];
            float al[2][4];
#pragma unroll
            for (int m = 0; m < 2; ++m)
#pragma unroll
                for (int i = 0; i < 4; ++i) {
                    float mx = fmaxf(fmaxf(sf[m][0][i], sf[m][1][i]), fmaxf(sf[m][2][i], sf[m][3][i]));
                    mx = fmaxf(mx, __shfl_xor(mx, 1));
                    mx = fmaxf(mx, __shfl_xor(mx, 2));
                    mx = fmaxf(mx, __shfl_xor(mx, 4));
                    mx = fmaxf(mx, __shfl_xor(mx, 8));
                    float mnew = fmaxf(m_run[m][i], mx);
                    al[m][i] = __expf(m_run[m][i] - mnew);
                    m_run[m][i] = mnew;
                }
            float rs[2][4];
#pragma unroll
            for (int m = 0; m < 2; ++m)
#pragma unroll
                for (int i = 0; i < 4; ++i) rs[m][i] = 0.f;
#pragma unroll
            for (int m = 0; m < 2; ++m)
#pragma unroll
                for (int n = 0; n < 4; ++n)
#pragma unroll
                    for (int i = 0; i < 4; ++i) {
                        float p = __expf(sf[m][n][i] - m_run[m][i]);
                        sf[m][n][i] = p;
                        rs[m][i] += p;
                    }
#pragma unroll
            for (int m = 0; m < 2; ++m)
#pragma unroll
                for (int i = 0; i < 4; ++i) {
                    float r2 = rs[m][i];
                    r2 += __shfl_xor(r2, 1);
                    r2 += __shfl_xor(r2, 2);
                    r2 += __shfl_xor(r2, 4);
                    r2 += __shfl_xor(r2, 8);
                    l_run[m][i] = l_run[m][i] * al[m][i] + r2;
                }
#pragma unroll
            for (int m = 0; m < 2; ++m)
#pragma unroll
                for (int n = 0; n < 4; ++n)
#pragma unroll
                    for (int i = 0; i < 4; ++i) o[m][n][i] *= al[m][i];

            // P round-trip through wave-private Ps[w]: no block barriers needed
#pragma unroll
            for (int m = 0; m < 2; ++m)
#pragma unroll
                for (int n = 0; n < 4; ++n)
#pragma unroll
                    for (int i = 0; i < 4; ++i) {
                        int row = m * 16 + lg * 4 + i;
                        int cb = ((n * 16 + l15) * 2) ^ ((row & 7) << 4);
                        *(unsigned short*)((char*)Ps[w] + row * 128 + cb) = f2bf(sf[m][n][i]);
                    }
#pragma unroll
            for (int ks = 0; ks < 2; ++ks) {
                short8 pa[2];
#pragma unroll
                for (int m = 0; m < 2; ++m) {
                    int row = m * 16 + l15;
                    int cb = (ks * 64 + lg * 16) ^ ((row & 7) << 4);
                    pa[m] = *(const short8*)((char*)Ps[w] + row * 128 + cb);
                }
                short8 vb[4];
#pragma unroll
                for (int n = 0; n < 4; ++n) {
                    int row = n * 16 + l15;
                    int cb = (keyl * 2 + ks * 64 + lg * 16) ^ ((row & 7) << 4);
                    vb[n] = *(const short8*)((char*)Vts + row * 256 + cb);
                }
#pragma unroll
                for (int m = 0; m < 2; ++m)
#pragma unroll
                    for (int n = 0; n < 4; ++n)
                        o[m][n] = __builtin_amdgcn_mfma_f32_16x16x32_bf16(pa[m], vb[n], o[m][n], 0, 0, 0);
            }
        }
    }

    unsigned short* aop = ao + ((size_t)(b * 256 + w * 32)) * 1024 + h * 64;
#pragma unroll
    for (int m = 0; m < 2; ++m)
#pragma unroll
        for (int n = 0; n < 4; ++n)
#pragma unroll
            for (int i = 0; i < 4; ++i) {
                int row = m * 16 + lg * 4 + i;
                int d = n * 16 + l15;
                aop[(size_t)row * 1024 + d] = f2bf(o[m][n][i] / l_run[m][i]);
            }
}

// ---------- launch ----------
extern "C" void kernel_launch(void* const* d_in, const int* in_sizes, int n_in,
                              void* d_out, int out_size, void* d_ws, size_t ws_size,
                              hipStream_t stream) {
    const float* x = (const float*)d_in[0];
    const int* mask = (const int*)d_in[1];
    const float* Wq = (const float*)d_in[2];
    const float* Wk = (const float*)d_in[3];
    const float* Wv = (const float*)d_in[4];
    const float* Wo = (const float*)d_in[5];
    float* out = (float*)d_out;

    char* ws = (char*)d_ws;
    size_t off = 0;
    auto alloc = [&](size_t bytes) -> char* {
        char* p = ws + off;
        off = (off + bytes + 255) & ~(size_t)255;
        return p;
    };
    unsigned short* xb = (unsigned short*)alloc((size_t)16384 * 1024 * 2);  // bf16 x; later aliased as attn_out
    unsigned short* wqb = (unsigned short*)alloc((size_t)1024 * 1024 * 2);
    unsigned short* wkb = (unsigned short*)alloc((size_t)1024 * 1024 * 2);
    unsigned short* wvb = (unsigned short*)alloc((size_t)1024 * 1024 * 2);
    unsigned short* wob = (unsigned short*)alloc((size_t)1024 * 1024 * 2);
    unsigned short* q = (unsigned short*)alloc((size_t)16384 * 1024 * 2);   // (B,H,S,64)
    unsigned short* k = (unsigned short*)alloc((size_t)16384 * 1024 * 2);   // (B,H,S,64)
    unsigned short* vt = (unsigned short*)alloc((size_t)16384 * 1024 * 2);  // (B,H,64,S)
    float* cosT = (float*)alloc(256 * 32 * 4);
    float* sinT = (float*)alloc(256 * 32 * 4);

    init_kernel<<<8192 + 2048 + 32, 256, 0, stream>>>(x, Wq, Wk, Wv, Wo,
                                                      xb, wqb, wkb, wvb, wob, cosT, sinT);

    gemm256_kernel<0><<<768, 512, 0, stream>>>(xb, wqb, wkb, wvb, q, k, vt, nullptr, cosT, sinT);
    attn_kernel<<<1024, 512, 0, stream>>>(q, k, vt, mask, xb /* attn_out, aliases xb */);
    gemm256_kernel<1><<<256, 512, 0, stream>>>(xb, wob, nullptr, nullptr, nullptr, nullptr, nullptr, out, cosT, sinT);

    (void)in_sizes; (void)n_in; (void)out_size; (void)ws_size;
}